// Round 8
// baseline (310.865 us; speedup 1.0000x reference)
//
#include <hip/hip_runtime.h>
#include <math.h>

// Problem constants (x: [2048, 2048, 3, 3] f32, bits=8)
// channel stride = h*w = 9 floats; group-block = 8 channels * 9 = 72
// consecutive floats; n = 37,748,736 floats; cells = n/8 = 4,718,592
// (cell = 8 channels at stride 9 for one (gb, hw)).
#define HW        9
#define GROUP     8
#define KEEP      4
#define DELTA     127.0f
#define INV_DELTA (1.0f / 127.0f)
#define GB_FLOATS 72

// ---------------- Kernel 1: global max|x| ----------------
__global__ void maxabs_kernel(const float4* __restrict__ x, unsigned* __restrict__ ws, int n4) {
    __shared__ float red[4];
    float m = 0.0f;
    int stride = gridDim.x * blockDim.x;
    #pragma unroll 4
    for (int i = blockIdx.x * blockDim.x + threadIdx.x; i < n4; i += stride) {
        float4 v = x[i];
        m = fmaxf(m, fmaxf(fmaxf(fabsf(v.x), fabsf(v.y)),
                           fmaxf(fabsf(v.z), fabsf(v.w))));
    }
    #pragma unroll
    for (int off = 32; off > 0; off >>= 1)
        m = fmaxf(m, __shfl_down(m, off, 64));
    int wave = threadIdx.x >> 6;
    if ((threadIdx.x & 63) == 0) red[wave] = m;
    __syncthreads();
    if (threadIdx.x == 0) {
        float b = fmaxf(fmaxf(red[0], red[1]), fmaxf(red[2], red[3]));
        atomicMax(ws, __float_as_uint(b));   // |x|>=0: float bit order == uint order
    }
}

// ---------------- Kernel 1.5: broadcast M, C through workspace ----------
// Hoists the per-block f64 tanh + __syncthreads out of the quant kernel
// entirely: quant becomes barrier-free and __shared__-free.
__global__ void prep_kernel(unsigned* __restrict__ ws) {
    if (threadIdx.x == 0) {
        // M = max|tanh(x)| = tanh(max|x|) (tanh odd+monotone; RNE symmetric)
        double mm = tanh((double)__uint_as_float(ws[0]));
        ws[1] = __float_as_uint((float)mm);
        ws[2] = __float_as_uint((float)(127.0 / mm));
    }
}

// Cold bit-exact reference path (identical to the passing kernel):
// t = (float)tanh(double x); y = t/M (f32 div); z = y*127; rint.
__device__ __attribute__((noinline)) float ref_rz(float xx, float M) {
    float td = (float)tanh((double)xx);
    float y  = td / M;
    return rintf(y * DELTA);
}

// Fast f32 tanh. Poly (|x|<=0.5): Taylor odd series through x^11,
// rel err <= ~2.5e-7. Exp form else: (E-1)/(E+1) with native exp + NR rcp.
__device__ __forceinline__ float fast_tanh(float x) {
    float ax  = fabsf(x);
    float axc = fminf(ax, 10.0f);
    float E   = __expf(2.0f * axc);
    float num = E - 1.0f;
    float den = E + 1.0f;
    float r0  = __builtin_amdgcn_rcpf(den);
    float r   = r0 * fmaf(-den, r0, 2.0f);      // one Newton step
    float tl  = copysignf(num * r, x);
    float s = x * x;
    float p = fmaf(s, 0.0035921280f, -0.0088632358f);
    p = fmaf(s, p, 0.021869488f);
    p = fmaf(s, p, -0.053968254f);
    p = fmaf(s, p, 0.13333334f);
    p = fmaf(s, p, -0.33333334f);
    float ts = fmaf(x * s, p, x);
    return (ax <= 0.5f) ? ts : tl;
}

__device__ __forceinline__ unsigned umx(unsigned a, unsigned b) { return a > b ? a : b; }
__device__ __forceinline__ unsigned umn(unsigned a, unsigned b) { return a < b ? a : b; }

// ---------------- Kernel 2: quantize + group top-4 mask ----------------
// Max-TLP structure: ONE THREAD PER CELL (8 floats at stride 9 within one
// 72-float group-block). No LDS data path, no barriers, no staging: pure
// load -> compute -> store. A wave's 64 cells span ~18 KB of contiguous
// input, so the 16 scattered-dword VMEM instrs per thread are absorbed by
// L1/L2 line reuse; TLP (6 waves/SIMD vs r4's 2) covers the latency.
// Numerics chain byte-identical to all previous passing rounds.
// Top-4 via distinct-key threshold (exact-equivalent to pairwise rank,
// verified r5): K_j = (|rz_j|<<3)|(7-j); keep j iff K_j >= T (4th-largest),
// via two descending 4-sorts + 5-candidate merge.
__global__ __launch_bounds__(256, 6) void quant_cell(const float* __restrict__ x,
                                                     float* __restrict__ out,
                                                     const unsigned* __restrict__ ws,
                                                     int n_cells) {
    int ci = blockIdx.x * 256 + threadIdx.x;
    if (ci >= n_cells) return;            // exact fit for this shape

    const float M = __uint_as_float(ws[1]);
    const float C = __uint_as_float(ws[2]);

    int gb = ci / 9;                      // magic-mul
    int hw = ci - gb * 9;
    const size_t base = (size_t)gb * GB_FLOATS + hw;
    const float* px = x + base;

    float v8[GROUP];
    unsigned K[GROUP];
    #pragma unroll
    for (int j = 0; j < GROUP; ++j) {
        float xx = px[9 * j];             // 8 dword loads, imm offsets 0..252
        float t  = fast_tanh(xx);
        float z  = t * C;
        float rz = rintf(z);                 // numpy round: half-to-even
        float d  = 0.5f - fabsf(z - rz);     // distance to nearest half-int
        if (d < fmaf(2e-6f, fabsf(z), 5e-7f))
            rz = ref_rz(xx, M);              // cold, bit-exact chain
        v8[j] = rz;
        K[j] = ((unsigned)fabsf(rz) << 3) | (unsigned)(7 - j);
    }

    unsigned s0 = K[0], s1 = K[1], s2 = K[2], s3 = K[3];
    unsigned s4 = K[4], s5 = K[5], s6 = K[6], s7 = K[7];
    #define CE_(a, b) { unsigned _h = umx(a, b), _l = umn(a, b); a = _h; b = _l; }
    CE_(s0, s1) CE_(s2, s3) CE_(s0, s2) CE_(s1, s3) CE_(s1, s2)
    CE_(s4, s5) CE_(s6, s7) CE_(s4, s6) CE_(s5, s7) CE_(s5, s6)
    #undef CE_
    unsigned T = umx(umx(umn(s0, s6), umn(s1, s5)),
                     umx(umn(s2, s4), umx(s3, s7)));

    float* po = out + base;
    #pragma unroll
    for (int j = 0; j < GROUP; ++j)
        po[9 * j] = (K[j] >= T) ? (v8[j] * INV_DELTA) : 0.0f;
}

extern "C" void kernel_launch(void* const* d_in, const int* in_sizes, int n_in,
                              void* d_out, int out_size, void* d_ws, size_t ws_size,
                              hipStream_t stream) {
    const float* x = (const float*)d_in[0];
    float* out = (float*)d_out;
    unsigned* ws = (unsigned*)d_ws;

    int n = in_sizes[0];                 // 37,748,736
    int n4 = n / 4;
    int n_cells = n / GROUP;             // 4,718,592

    hipMemsetAsync(ws, 0, sizeof(unsigned), stream);

    maxabs_kernel<<<2048, 256, 0, stream>>>((const float4*)x, ws, n4);
    prep_kernel<<<1, 64, 0, stream>>>(ws);

    int blocks_q = (n_cells + 255) / 256;   // 18432, exact fit
    quant_cell<<<blocks_q, 256, 0, stream>>>(x, out, ws, n_cells);
}